// Round 1
// baseline (1303.508 us; speedup 1.0000x reference)
//
#include <hip/hip_runtime.h>
#include <hip/hip_bf16.h>
#include <math.h>

#define T_ 12
#define E_ 8192
#define H_ 256
#define V_ 800
#define B_ 256
#define NB_ 8
#define M_ (T_*E_)

__device__ __forceinline__ float sigmoidf_(float x) {
    return 1.0f / (1.0f + expf(-x));
}

// Zero the padding row (slot 0) of h and u. ws/out are poisoned 0xAA each call.
__global__ __launch_bounds__(256) void k_init(float* __restrict__ h, float* __restrict__ u) {
    int d = threadIdx.x;
    h[d] = 0.0f;
    u[d] = 0.0f;
}

// Per message row e at depth t:
//   sum_h[e]  = sum_j h[nei[j]]
//   sum_g[e]  = sum_j sigmoid(eWr[xid[e]] + u[nei[j]] + bur) * h[nei[j]]
// where u = h @ Ur was computed at message-production time.
__global__ __launch_bounds__(256) void k_gate(
    int t,
    const int* __restrict__ x_ids, const int* __restrict__ nei_idx,
    const float* __restrict__ h, const float* __restrict__ u,
    const float* __restrict__ eWr, const float* __restrict__ bur,
    float* __restrict__ sumh, float* __restrict__ sumg)
{
    const int e = blockIdx.x;
    const int d = threadIdx.x;
    __shared__ int idx[NB_];
    if (d < NB_) idx[d] = nei_idx[((size_t)t * E_ + e) * NB_ + d];
    __syncthreads();
    const int xid = x_ids[t * E_ + e];
    const float r1 = eWr[(size_t)xid * H_ + d] + bur[d];
    float sh = 0.0f, sg = 0.0f;
#pragma unroll
    for (int j = 0; j < NB_; ++j) {
        const size_t off = (size_t)idx[j] * H_ + d;
        const float hv = h[off];
        const float uv = u[off];
        sh += hv;
        const float r = sigmoidf_(r1 + uv);
        sg = fmaf(r, hv, sg);
    }
    sumh[(size_t)e * H_ + d] = sh;
    sumg[(size_t)e * H_ + d] = sg;
}

enum { MODE_PLAIN = 0, MODE_Z = 1, MODE_H = 2 };

// C[M x 256] = A[M x 256] @ B[256 x 256] (both row-major), fused epilogues.
// MODE_Z: z = sigmoid(acc + G[xid[m]] + bias)
// MODE_H: pre = tanh(acc + G[xid[m]] + bias); C = (1-z)*sumh + z*pre
template<int MODE>
__global__ __launch_bounds__(256) void gemm256(
    const float* __restrict__ A, const float* __restrict__ B,
    float* __restrict__ C, int M,
    const int* __restrict__ xid, const float* __restrict__ G,
    const float* __restrict__ bias,
    const float* __restrict__ zbuf, const float* __restrict__ shbuf)
{
    __shared__ float As[16][64];   // [k][m]
    __shared__ float Bs[16][64];   // [k][n]
    const int tid = threadIdx.x;
    const int bm = blockIdx.x * 64;
    const int bn = blockIdx.y * 64;

    const int a_m = tid & 63;           // wave lanes cover 64 distinct m -> 2-way bank (free)
    const int a_k = (tid >> 6) << 2;
    const int b_k = tid >> 4;
    const int b_n = (tid & 15) << 2;
    const int tx = tid & 15, ty = tid >> 4;

    float acc[4][4] = {};
    const bool a_ok = (bm + a_m) < M;
    const float* Ap = A + (size_t)(bm + a_m) * H_ + a_k;
    const float* Bp = B + (size_t)b_k * H_ + bn + b_n;

    for (int k0 = 0; k0 < H_; k0 += 16) {
        float4 av = a_ok ? *(const float4*)(Ap + k0) : make_float4(0.f, 0.f, 0.f, 0.f);
        float4 bv = *(const float4*)(Bp + (size_t)k0 * H_);
        __syncthreads();
        As[a_k + 0][a_m] = av.x;
        As[a_k + 1][a_m] = av.y;
        As[a_k + 2][a_m] = av.z;
        As[a_k + 3][a_m] = av.w;
        *(float4*)&Bs[b_k][b_n] = bv;
        __syncthreads();
#pragma unroll
        for (int k = 0; k < 16; ++k) {
            const float4 a4 = *(const float4*)&As[k][ty << 2];
            const float4 b4 = *(const float4*)&Bs[k][tx << 2];
            const float ar[4] = {a4.x, a4.y, a4.z, a4.w};
            const float br[4] = {b4.x, b4.y, b4.z, b4.w};
#pragma unroll
            for (int i = 0; i < 4; ++i)
#pragma unroll
                for (int j = 0; j < 4; ++j)
                    acc[i][j] = fmaf(ar[i], br[j], acc[i][j]);
        }
    }

    const int col = bn + (tx << 2);
#pragma unroll
    for (int i = 0; i < 4; ++i) {
        const int row = bm + (ty << 2) + i;
        if (row >= M) break;
        float vv[4];
        if (MODE == MODE_PLAIN) {
#pragma unroll
            for (int j = 0; j < 4; ++j) vv[j] = acc[i][j];
        } else {
            const float* g = G + (size_t)xid[row] * H_ + col;
#pragma unroll
            for (int j = 0; j < 4; ++j) {
                const float pre = acc[i][j] + g[j] + bias[col + j];
                if (MODE == MODE_Z) {
                    vv[j] = sigmoidf_(pre);
                } else {
                    const float p = tanhf(pre);
                    const float z = zbuf[(size_t)row * H_ + col + j];
                    const float sh = shbuf[(size_t)row * H_ + col + j];
                    vv[j] = (1.0f - z) * sh + z * p;
                }
            }
        }
        *(float4*)(C + (size_t)row * H_ + col) = make_float4(vv[0], vv[1], vv[2], vv[3]);
    }
}

// root_vecs[b] = relu(eWo[root_wid[b]] + sum_nei @ Wo_bot + bo)
__global__ __launch_bounds__(256) void k_root(
    const int* __restrict__ root_wid, const int* __restrict__ root_nei,
    const float* __restrict__ h, const float* __restrict__ eWo,
    const float* __restrict__ Wo, const float* __restrict__ bo,
    float* __restrict__ out)
{
    const int b = blockIdx.x, d = threadIdx.x;
    __shared__ float sn[H_];
    __shared__ int idx[NB_];
    if (d < NB_) idx[d] = root_nei[b * NB_ + d];
    __syncthreads();
    float s = 0.0f;
#pragma unroll
    for (int j = 0; j < NB_; ++j) s += h[(size_t)idx[j] * H_ + d];
    sn[d] = s;
    __syncthreads();
    float acc = eWo[(size_t)root_wid[b] * H_ + d] + bo[d];
    for (int k = 0; k < H_; ++k)
        acc = fmaf(sn[k], Wo[(size_t)(H_ + k) * H_ + d], acc);
    out[(size_t)b * H_ + d] = fmaxf(acc, 0.0f);
}

extern "C" void kernel_launch(void* const* d_in, const int* in_sizes, int n_in,
                              void* d_out, int out_size, void* d_ws, size_t ws_size,
                              hipStream_t stream)
{
    const int*   x_ids    = (const int*)d_in[0];
    const int*   nei_idx  = (const int*)d_in[1];
    const int*   root_wid = (const int*)d_in[2];
    const int*   root_nei = (const int*)d_in[3];
    const float* emb      = (const float*)d_in[4];
    const float* Wz       = (const float*)d_in[5];
    const float* bz       = (const float*)d_in[6];
    const float* Wr       = (const float*)d_in[7];
    const float* Ur       = (const float*)d_in[8];
    const float* bur      = (const float*)d_in[9];
    const float* Wh       = (const float*)d_in[10];
    const float* bh       = (const float*)d_in[11];
    const float* Wo       = (const float*)d_in[12];
    const float* bo       = (const float*)d_in[13];

    float* h        = (float*)d_out;                      // [(1+M), H]
    float* root_out = h + (size_t)(1 + M_) * H_;          // [B, H]

    float* u    = (float*)d_ws;                           // [(1+M), H]  h @ Ur
    float* sumh = u    + (size_t)(1 + M_) * H_;           // [E, H]
    float* sumg = sumh + (size_t)E_ * H_;                 // [E, H]
    float* zb   = sumg + (size_t)E_ * H_;                 // [E, H]
    float* eWr  = zb   + (size_t)E_ * H_;                 // [V, H] emb @ Wr
    float* eWz  = eWr  + (size_t)V_ * H_;                 // [V, H] emb @ Wz_top
    float* eWh  = eWz  + (size_t)V_ * H_;                 // [V, H] emb @ Wh_top
    float* eWo  = eWh  + (size_t)V_ * H_;                 // [V, H] emb @ Wo_top

    const dim3 blk(256);

    k_init<<<dim3(1), blk, 0, stream>>>(h, u);

    const dim3 gpre((V_ + 63) / 64, 4);
    gemm256<MODE_PLAIN><<<gpre, blk, 0, stream>>>(emb, Wr, eWr, V_, nullptr, nullptr, nullptr, nullptr, nullptr);
    gemm256<MODE_PLAIN><<<gpre, blk, 0, stream>>>(emb, Wz, eWz, V_, nullptr, nullptr, nullptr, nullptr, nullptr);
    gemm256<MODE_PLAIN><<<gpre, blk, 0, stream>>>(emb, Wh, eWh, V_, nullptr, nullptr, nullptr, nullptr, nullptr);
    gemm256<MODE_PLAIN><<<gpre, blk, 0, stream>>>(emb, Wo, eWo, V_, nullptr, nullptr, nullptr, nullptr, nullptr);

    const dim3 gstep(E_ / 64, 4);
    for (int t = 0; t < T_; ++t) {
        float* h_t = h + (size_t)(1 + t * E_) * H_;
        float* u_t = u + (size_t)(1 + t * E_) * H_;
        k_gate<<<dim3(E_), blk, 0, stream>>>(t, x_ids, nei_idx, h, u, eWr, bur, sumh, sumg);
        gemm256<MODE_Z><<<gstep, blk, 0, stream>>>(sumh, Wz + 256 * H_, zb, E_,
                                                   x_ids + t * E_, eWz, bz, nullptr, nullptr);
        gemm256<MODE_H><<<gstep, blk, 0, stream>>>(sumg, Wh + 256 * H_, h_t, E_,
                                                   x_ids + t * E_, eWh, bh, zb, sumh);
        gemm256<MODE_PLAIN><<<gstep, blk, 0, stream>>>(h_t, Ur, u_t, E_,
                                                       nullptr, nullptr, nullptr, nullptr, nullptr);
    }

    k_root<<<dim3(B_), blk, 0, stream>>>(root_wid, root_nei, h, eWo, Wo, bo, root_out);
}

// Round 2
// 991.308 us; speedup vs baseline: 1.3149x; 1.3149x over previous
//
#include <hip/hip_runtime.h>
#include <hip/hip_bf16.h>
#include <math.h>

#define T_ 12
#define E_ 8192
#define H_ 256
#define V_ 800
#define B_ 256
#define NB_ 8
#define M_ (T_*E_)

typedef __attribute__((ext_vector_type(8))) short bf16x8;
typedef __attribute__((ext_vector_type(4))) float f32x4;

__device__ __forceinline__ float sigmoidf_(float x) {
    return 1.0f / (1.0f + expf(-x));
}

// RNE f32 -> bf16 bits (no NaN special-casing needed for this workload)
__device__ __forceinline__ short f2bf(float x) {
    unsigned u = __float_as_uint(x);
    unsigned r = (u + 0x7fffu + ((u >> 16) & 1u)) >> 16;
    return (short)r;
}

// Load 8 consecutive f32 and convert to a bf16x8 A-fragment.
__device__ __forceinline__ bf16x8 cvt8(const float* __restrict__ p) {
    f32x4 lo = *(const f32x4*)p;
    f32x4 hi = *(const f32x4*)(p + 4);
    bf16x8 r;
    r[0] = f2bf(lo.x); r[1] = f2bf(lo.y); r[2] = f2bf(lo.z); r[3] = f2bf(lo.w);
    r[4] = f2bf(hi.x); r[5] = f2bf(hi.y); r[6] = f2bf(hi.z); r[7] = f2bf(hi.w);
    return r;
}

// Zero the padding row (slot 0) of h and u (ws/out are poisoned 0xAA each call).
__global__ __launch_bounds__(256) void k_init(float* __restrict__ h, float* __restrict__ u) {
    int d = threadIdx.x;
    h[d] = 0.0f;
    u[d] = 0.0f;
}

// Weight prep: Wzt[n][k] = Wz[256+k][n], Wht[n][k] = Wh[256+k][n], Urt[n][k] = Ur[k][n], bf16.
__global__ __launch_bounds__(256) void k_wconv(
    const float* __restrict__ Wz, const float* __restrict__ Wh, const float* __restrict__ Ur,
    short* __restrict__ Wzt, short* __restrict__ Wht, short* __restrict__ Urt)
{
    int tid = blockIdx.x * 256 + threadIdx.x;
    int w = tid >> 16;
    int idx = tid & 65535;
    int n = idx >> 8, k = idx & 255;
    if (w == 0)      Wzt[idx] = f2bf(Wz[(size_t)(256 + k) * H_ + n]);
    else if (w == 1) Wht[idx] = f2bf(Wh[(size_t)(256 + k) * H_ + n]);
    else             Urt[idx] = f2bf(Ur[(size_t)k * H_ + n]);
    (void)n;
}

// Per message row e at depth t:
//   sumh[e] = sum_j h[nei[j]]
//   sumg[e] = sum_j sigmoid(eWr[xid[e]] + bur + u[nei[j]]) * h[nei[j]]
__global__ __launch_bounds__(256) void k_gate(
    int t,
    const int* __restrict__ x_ids, const int* __restrict__ nei_idx,
    const float* __restrict__ h, const float* __restrict__ u,
    const float* __restrict__ eWr, const float* __restrict__ bur,
    float* __restrict__ sumh, float* __restrict__ sumg)
{
    const int e = blockIdx.x;
    const int d = threadIdx.x;
    __shared__ int idx[NB_];
    if (d < NB_) idx[d] = nei_idx[((size_t)t * E_ + e) * NB_ + d];
    __syncthreads();
    const int xid = x_ids[t * E_ + e];
    const float r1 = eWr[(size_t)xid * H_ + d] + bur[d];
    float sh = 0.0f, sg = 0.0f;
#pragma unroll
    for (int j = 0; j < NB_; ++j) {
        const size_t off = (size_t)idx[j] * H_ + d;
        const float hv = h[off];
        const float uv = u[off];
        sh += hv;
        const float r = sigmoidf_(r1 + uv);
        sg = fmaf(r, hv, sg);
    }
    sumh[(size_t)e * H_ + d] = sh;
    sumg[(size_t)e * H_ + d] = sg;
}

// Fused Z+H GEMMs via bf16 MFMA, LDS-free (A/B are L2-resident).
// P1 = sumh @ WzBot, P2 = sumg @ WhBot  (weights pre-transposed [n][k] bf16)
// z = sigmoid(P1 + eWz[xid] + bz); pre = tanh(P2 + eWh[xid] + bh)
// h_t = (1-z)*sumh + z*pre
// Block: 256 thr = 4 waves; M-tile 16 (block row), each wave covers 64 cols.
__global__ __launch_bounds__(256) void k_zh(
    const float* __restrict__ sumh, const float* __restrict__ sumg,
    const short* __restrict__ Wzt, const short* __restrict__ Wht,
    const int* __restrict__ xid_t,
    const float* __restrict__ eWz, const float* __restrict__ eWh,
    const float* __restrict__ bzv, const float* __restrict__ bhv,
    float* __restrict__ h_t)
{
    const int wave = threadIdx.x >> 6;
    const int lane = threadIdx.x & 63;
    const int quad = lane >> 4, c = lane & 15;
    const int bm = blockIdx.x * 16;
    const int n0 = wave * 64;
    const int m = bm + c;
    const int kq = quad * 8;

    f32x4 accZ[4], accH[4];
#pragma unroll
    for (int i = 0; i < 4; ++i) { accZ[i] = (f32x4)(0.0f); accH[i] = (f32x4)(0.0f); }

#pragma unroll
    for (int k0 = 0; k0 < H_; k0 += 32) {
        const bf16x8 a1 = cvt8(sumh + (size_t)m * H_ + k0 + kq);
        const bf16x8 a2 = cvt8(sumg + (size_t)m * H_ + k0 + kq);
#pragma unroll
        for (int ni = 0; ni < 4; ++ni) {
            const size_t boff = (size_t)(n0 + ni * 16 + c) * H_ + k0 + kq;
            const bf16x8 b1 = *(const bf16x8*)(Wzt + boff);
            const bf16x8 b2 = *(const bf16x8*)(Wht + boff);
            accZ[ni] = __builtin_amdgcn_mfma_f32_16x16x32_bf16(a1, b1, accZ[ni], 0, 0, 0);
            accH[ni] = __builtin_amdgcn_mfma_f32_16x16x32_bf16(a2, b2, accH[ni], 0, 0, 0);
        }
    }

#pragma unroll
    for (int reg = 0; reg < 4; ++reg) {
        const int row = bm + quad * 4 + reg;
        const int xw = xid_t[row];
#pragma unroll
        for (int ni = 0; ni < 4; ++ni) {
            const int col = n0 + ni * 16 + c;
            const float z = sigmoidf_(accZ[ni][reg] + eWz[(size_t)xw * H_ + col] + bzv[col]);
            const float pre = tanhf(accH[ni][reg] + eWh[(size_t)xw * H_ + col] + bhv[col]);
            const float sh = sumh[(size_t)row * H_ + col];
            h_t[(size_t)row * H_ + col] = (1.0f - z) * sh + z * pre;
        }
    }
}

// u_t = h_t @ Ur  (Urt pre-transposed [n][k] bf16), h_t read fp32 + inline cvt.
__global__ __launch_bounds__(256) void k_ur(
    const float* __restrict__ h_t, const short* __restrict__ Urt,
    float* __restrict__ u_t)
{
    const int wave = threadIdx.x >> 6;
    const int lane = threadIdx.x & 63;
    const int quad = lane >> 4, c = lane & 15;
    const int bm = blockIdx.x * 16;
    const int n0 = wave * 64;
    const int m = bm + c;
    const int kq = quad * 8;

    f32x4 acc[4];
#pragma unroll
    for (int i = 0; i < 4; ++i) acc[i] = (f32x4)(0.0f);

#pragma unroll
    for (int k0 = 0; k0 < H_; k0 += 32) {
        const bf16x8 a = cvt8(h_t + (size_t)m * H_ + k0 + kq);
#pragma unroll
        for (int ni = 0; ni < 4; ++ni) {
            const size_t boff = (size_t)(n0 + ni * 16 + c) * H_ + k0 + kq;
            const bf16x8 b = *(const bf16x8*)(Urt + boff);
            acc[ni] = __builtin_amdgcn_mfma_f32_16x16x32_bf16(a, b, acc[ni], 0, 0, 0);
        }
    }

#pragma unroll
    for (int reg = 0; reg < 4; ++reg) {
        const int row = bm + quad * 4 + reg;
#pragma unroll
        for (int ni = 0; ni < 4; ++ni) {
            const int col = n0 + ni * 16 + c;
            u_t[(size_t)row * H_ + col] = acc[ni][reg];
        }
    }
}

// fp32 vector GEMM for the small prelude products eW* = emb @ W_top (proven correct R1).
enum { MODE_PLAIN = 0 };
template<int MODE>
__global__ __launch_bounds__(256) void gemm256(
    const float* __restrict__ A, const float* __restrict__ B,
    float* __restrict__ C, int M)
{
    __shared__ float As[16][64];
    __shared__ float Bs[16][64];
    const int tid = threadIdx.x;
    const int bm = blockIdx.x * 64;
    const int bn = blockIdx.y * 64;

    const int a_m = tid & 63;
    const int a_k = (tid >> 6) << 2;
    const int b_k = tid >> 4;
    const int b_n = (tid & 15) << 2;
    const int tx = tid & 15, ty = tid >> 4;

    float acc[4][4] = {};
    const bool a_ok = (bm + a_m) < M;
    const float* Ap = A + (size_t)(bm + a_m) * H_ + a_k;
    const float* Bp = B + (size_t)b_k * H_ + bn + b_n;

    for (int k0 = 0; k0 < H_; k0 += 16) {
        float4 av = a_ok ? *(const float4*)(Ap + k0) : make_float4(0.f, 0.f, 0.f, 0.f);
        float4 bv = *(const float4*)(Bp + (size_t)k0 * H_);
        __syncthreads();
        As[a_k + 0][a_m] = av.x;
        As[a_k + 1][a_m] = av.y;
        As[a_k + 2][a_m] = av.z;
        As[a_k + 3][a_m] = av.w;
        *(float4*)&Bs[b_k][b_n] = bv;
        __syncthreads();
#pragma unroll
        for (int k = 0; k < 16; ++k) {
            const float4 a4 = *(const float4*)&As[k][ty << 2];
            const float4 b4 = *(const float4*)&Bs[k][tx << 2];
            const float ar[4] = {a4.x, a4.y, a4.z, a4.w};
            const float br[4] = {b4.x, b4.y, b4.z, b4.w};
#pragma unroll
            for (int i = 0; i < 4; ++i)
#pragma unroll
                for (int j = 0; j < 4; ++j)
                    acc[i][j] = fmaf(ar[i], br[j], acc[i][j]);
        }
    }

    const int col = bn + (tx << 2);
#pragma unroll
    for (int i = 0; i < 4; ++i) {
        const int row = bm + (ty << 2) + i;
        if (row >= M) break;
        *(float4*)(C + (size_t)row * H_ + col) =
            make_float4(acc[i][0], acc[i][1], acc[i][2], acc[i][3]);
    }
}

// root_vecs[b] = relu(eWo[root_wid[b]] + sum_nei @ Wo_bot + bo)
__global__ __launch_bounds__(256) void k_root(
    const int* __restrict__ root_wid, const int* __restrict__ root_nei,
    const float* __restrict__ h, const float* __restrict__ eWo,
    const float* __restrict__ Wo, const float* __restrict__ bo,
    float* __restrict__ out)
{
    const int b = blockIdx.x, d = threadIdx.x;
    __shared__ float sn[H_];
    __shared__ int idx[NB_];
    if (d < NB_) idx[d] = root_nei[b * NB_ + d];
    __syncthreads();
    float s = 0.0f;
#pragma unroll
    for (int j = 0; j < NB_; ++j) s += h[(size_t)idx[j] * H_ + d];
    sn[d] = s;
    __syncthreads();
    float acc = eWo[(size_t)root_wid[b] * H_ + d] + bo[d];
    for (int k = 0; k < H_; ++k)
        acc = fmaf(sn[k], Wo[(size_t)(H_ + k) * H_ + d], acc);
    out[(size_t)b * H_ + d] = fmaxf(acc, 0.0f);
}

extern "C" void kernel_launch(void* const* d_in, const int* in_sizes, int n_in,
                              void* d_out, int out_size, void* d_ws, size_t ws_size,
                              hipStream_t stream)
{
    const int*   x_ids    = (const int*)d_in[0];
    const int*   nei_idx  = (const int*)d_in[1];
    const int*   root_wid = (const int*)d_in[2];
    const int*   root_nei = (const int*)d_in[3];
    const float* emb      = (const float*)d_in[4];
    const float* Wz       = (const float*)d_in[5];
    const float* bz       = (const float*)d_in[6];
    const float* Wr       = (const float*)d_in[7];
    const float* Ur       = (const float*)d_in[8];
    const float* bur      = (const float*)d_in[9];
    const float* Wh       = (const float*)d_in[10];
    const float* bh       = (const float*)d_in[11];
    const float* Wo       = (const float*)d_in[12];
    const float* bo       = (const float*)d_in[13];

    float* h        = (float*)d_out;                      // [(1+M), H]
    float* root_out = h + (size_t)(1 + M_) * H_;          // [B, H]

    float* u    = (float*)d_ws;                           // [(1+M), H]  h @ Ur
    float* sumh = u    + (size_t)(1 + M_) * H_;           // [E, H]
    float* sumg = sumh + (size_t)E_ * H_;                 // [E, H]
    float* eWr  = sumg + (size_t)E_ * H_;                 // [V, H] emb @ Wr
    float* eWz  = eWr  + (size_t)V_ * H_;                 // [V, H] emb @ Wz_top
    float* eWh  = eWz  + (size_t)V_ * H_;                 // [V, H] emb @ Wh_top
    float* eWo  = eWh  + (size_t)V_ * H_;                 // [V, H] emb @ Wo_top
    short* Wzt  = (short*)(eWo + (size_t)V_ * H_);        // [256,256] bf16, transposed bottom Wz
    short* Wht  = Wzt + 65536;
    short* Urt  = Wht + 65536;

    const dim3 blk(256);

    k_init<<<dim3(1), blk, 0, stream>>>(h, u);
    k_wconv<<<dim3(768), blk, 0, stream>>>(Wz, Wh, Ur, Wzt, Wht, Urt);

    const dim3 gpre((V_ + 63) / 64, 4);
    gemm256<MODE_PLAIN><<<gpre, blk, 0, stream>>>(emb, Wr, eWr, V_);
    gemm256<MODE_PLAIN><<<gpre, blk, 0, stream>>>(emb, Wz, eWz, V_);
    gemm256<MODE_PLAIN><<<gpre, blk, 0, stream>>>(emb, Wh, eWh, V_);
    gemm256<MODE_PLAIN><<<gpre, blk, 0, stream>>>(emb, Wo, eWo, V_);

    for (int t = 0; t < T_; ++t) {
        float* h_t = h + (size_t)(1 + t * E_) * H_;
        float* u_t = u + (size_t)(1 + t * E_) * H_;
        k_gate<<<dim3(E_), blk, 0, stream>>>(t, x_ids, nei_idx, h, u, eWr, bur, sumh, sumg);
        k_zh<<<dim3(E_ / 16), blk, 0, stream>>>(sumh, sumg, Wzt, Wht,
                                                x_ids + t * E_, eWz, eWh, bz, bh, h_t);
        k_ur<<<dim3(E_ / 16), blk, 0, stream>>>(h_t, Urt, u_t);
    }

    k_root<<<dim3(B_), blk, 0, stream>>>(root_wid, root_nei, h, eWo, Wo, bo, root_out);
}

// Round 3
// 847.121 us; speedup vs baseline: 1.5388x; 1.1702x over previous
//
#include <hip/hip_runtime.h>
#include <hip/hip_bf16.h>
#include <math.h>

#define T_ 12
#define E_ 8192
#define H_ 256
#define V_ 800
#define B_ 256
#define NB_ 8
#define M_ (T_*E_)
#define TM 16            // message rows per k_step block
#define HP (H_ + 8)      // bf16 LDS row pad: +16B keeps b128 alignment, breaks 16-way bank conflict

typedef __attribute__((ext_vector_type(8))) short bf16x8;
typedef __attribute__((ext_vector_type(4))) float f32x4;

__device__ __forceinline__ float sigmoidf_(float x) {
    return 1.0f / (1.0f + expf(-x));
}

// RNE f32 -> bf16 bits
__device__ __forceinline__ short f2bf(float x) {
    unsigned u = __float_as_uint(x);
    unsigned r = (u + 0x7fffu + ((u >> 16) & 1u)) >> 16;
    return (short)r;
}

// Zero the padding row (slot 0) of h and u (ws/out are poisoned 0xAA each call).
__global__ __launch_bounds__(256) void k_init(float* __restrict__ h, float* __restrict__ u) {
    int d = threadIdx.x;
    h[d] = 0.0f;
    u[d] = 0.0f;
}

// Weight prep: Wzt[n][k] = Wz[256+k][n], Wht[n][k] = Wh[256+k][n], Urt[n][k] = Ur[k][n], bf16.
__global__ __launch_bounds__(256) void k_wconv(
    const float* __restrict__ Wz, const float* __restrict__ Wh, const float* __restrict__ Ur,
    short* __restrict__ Wzt, short* __restrict__ Wht, short* __restrict__ Urt)
{
    int tid = blockIdx.x * 256 + threadIdx.x;
    int w = tid >> 16;
    int idx = tid & 65535;
    int n = idx >> 8, k = idx & 255;
    if (w == 0)      Wzt[idx] = f2bf(Wz[(size_t)(256 + k) * H_ + n]);
    else if (w == 1) Wht[idx] = f2bf(Wh[(size_t)(256 + k) * H_ + n]);
    else             Urt[idx] = f2bf(Ur[(size_t)k * H_ + n]);
}

// Batched prelude: eW*[v] = emb[v] @ Btop + bias  (z selects table)
__global__ __launch_bounds__(256) void gemm_pre(
    const float* __restrict__ emb,
    const float* __restrict__ Wr, const float* __restrict__ Wz,
    const float* __restrict__ Wh, const float* __restrict__ Wo,
    const float* __restrict__ bur, const float* __restrict__ bz,
    const float* __restrict__ bh, const float* __restrict__ bo,
    float* __restrict__ eWr, float* __restrict__ eWz,
    float* __restrict__ eWh, float* __restrict__ eWo)
{
    const float* Bm; const float* bias; float* C;
    switch (blockIdx.z) {
        case 0: Bm = Wr; bias = bur; C = eWr; break;
        case 1: Bm = Wz; bias = bz;  C = eWz; break;
        case 2: Bm = Wh; bias = bh;  C = eWh; break;
        default: Bm = Wo; bias = bo; C = eWo; break;
    }
    __shared__ float As[16][64];
    __shared__ float Bs[16][64];
    const int tid = threadIdx.x;
    const int bm = blockIdx.x * 64;
    const int bn = blockIdx.y * 64;
    const int a_m = tid & 63;
    const int a_k = (tid >> 6) << 2;
    const int b_k = tid >> 4;
    const int b_n = (tid & 15) << 2;
    const int tx = tid & 15, ty = tid >> 4;

    float acc[4][4] = {};
    const bool a_ok = (bm + a_m) < V_;
    const float* Ap = emb + (size_t)(bm + a_m) * H_ + a_k;
    const float* Bp = Bm + (size_t)b_k * H_ + bn + b_n;

    for (int k0 = 0; k0 < H_; k0 += 16) {
        float4 av = a_ok ? *(const float4*)(Ap + k0) : make_float4(0.f, 0.f, 0.f, 0.f);
        float4 bv = *(const float4*)(Bp + (size_t)k0 * H_);
        __syncthreads();
        As[a_k + 0][a_m] = av.x;
        As[a_k + 1][a_m] = av.y;
        As[a_k + 2][a_m] = av.z;
        As[a_k + 3][a_m] = av.w;
        *(float4*)&Bs[b_k][b_n] = bv;
        __syncthreads();
#pragma unroll
        for (int k = 0; k < 16; ++k) {
            const float4 a4 = *(const float4*)&As[k][ty << 2];
            const float4 b4 = *(const float4*)&Bs[k][tx << 2];
            const float ar[4] = {a4.x, a4.y, a4.z, a4.w};
            const float br[4] = {b4.x, b4.y, b4.z, b4.w};
#pragma unroll
            for (int i = 0; i < 4; ++i)
#pragma unroll
                for (int j = 0; j < 4; ++j)
                    acc[i][j] = fmaf(ar[i], br[j], acc[i][j]);
        }
    }

    const int col = bn + (tx << 2);
#pragma unroll
    for (int i = 0; i < 4; ++i) {
        const int row = bm + (ty << 2) + i;
        if (row >= V_) break;
        *(float4*)(C + (size_t)row * H_ + col) =
            make_float4(acc[i][0] + bias[col], acc[i][1] + bias[col + 1],
                        acc[i][2] + bias[col + 2], acc[i][3] + bias[col + 3]);
    }
}

// Fully fused step: gather + GRU (z/h MFMA) + h-write + Ur MFMA + u-write.
// Tables eWr/eWz/eWh already include their biases.
__global__ __launch_bounds__(256) void k_step(
    int t,
    const int* __restrict__ x_ids, const int* __restrict__ nei_idx,
    float* __restrict__ h, float* __restrict__ u,
    const float* __restrict__ eWr, const float* __restrict__ eWz,
    const float* __restrict__ eWh,
    const short* __restrict__ Wzt, const short* __restrict__ Wht,
    const short* __restrict__ Urt,
    int do_ur)
{
    __shared__ int   idx[TM][NB_];
    __shared__ int   xw[TM];
    __shared__ float shF[TM][H_];   // sumh fp32 (epilogue)
    __shared__ short shB[TM][HP];   // sumh bf16 (A-frag for Wz GEMM)
    __shared__ short sgB[TM][HP];   // sumg bf16 (A-frag for Wh GEMM)
    __shared__ short hB[TM][HP];    // h_t bf16 (A-frag for Ur GEMM)

    const int tid = threadIdx.x;
    const int e0 = blockIdx.x * TM;

    if (tid < TM * NB_) {
        int r = tid >> 3, j = tid & 7;
        idx[r][j] = nei_idx[((size_t)t * E_ + e0 + r) * NB_ + j];
    }
    if (tid < TM) xw[tid] = x_ids[t * E_ + e0 + tid];
    __syncthreads();

    // ---- gather phase: thread = one column, loop over TM rows ----
    {
        const int c = tid;
#pragma unroll 2
        for (int r = 0; r < TM; ++r) {
            const float r1 = eWr[(size_t)xw[r] * H_ + c];   // includes bur
            float sh = 0.0f, sg = 0.0f;
#pragma unroll
            for (int j = 0; j < NB_; ++j) {
                const size_t off = (size_t)idx[r][j] * H_ + c;
                const float hv = h[off];
                const float uv = u[off];
                sh += hv;
                sg = fmaf(sigmoidf_(r1 + uv), hv, sg);
            }
            shF[r][c] = sh;
            shB[r][c] = f2bf(sh);
            sgB[r][c] = f2bf(sg);
        }
    }
    __syncthreads();

    // ---- MFMA phase 1: P1 = sumh @ WzBot, P2 = sumg @ WhBot ----
    const int lane = tid & 63;
    const int wave = tid >> 6;
    const int quad = lane >> 4, c = lane & 15;
    const int n0 = wave * 64;
    const int kq = quad * 8;

    f32x4 accZ[4], accH[4];
#pragma unroll
    for (int i = 0; i < 4; ++i) { accZ[i] = (f32x4)(0.0f); accH[i] = (f32x4)(0.0f); }

#pragma unroll
    for (int k0 = 0; k0 < H_; k0 += 32) {
        const bf16x8 a1 = *(const bf16x8*)&shB[c][k0 + kq];
        const bf16x8 a2 = *(const bf16x8*)&sgB[c][k0 + kq];
#pragma unroll
        for (int ni = 0; ni < 4; ++ni) {
            const size_t boff = (size_t)(n0 + ni * 16 + c) * H_ + k0 + kq;
            const bf16x8 b1 = *(const bf16x8*)(Wzt + boff);
            const bf16x8 b2 = *(const bf16x8*)(Wht + boff);
            accZ[ni] = __builtin_amdgcn_mfma_f32_16x16x32_bf16(a1, b1, accZ[ni], 0, 0, 0);
            accH[ni] = __builtin_amdgcn_mfma_f32_16x16x32_bf16(a2, b2, accH[ni], 0, 0, 0);
        }
    }

    // ---- epilogue: h_t = (1-z)*sumh + z*pre ----
    float* h_t = h + (size_t)(1 + t * E_) * H_;
#pragma unroll
    for (int reg = 0; reg < 4; ++reg) {
        const int r = quad * 4 + reg;
        const int xr = xw[r];
#pragma unroll
        for (int ni = 0; ni < 4; ++ni) {
            const int col = n0 + ni * 16 + c;
            const float z   = sigmoidf_(accZ[ni][reg] + eWz[(size_t)xr * H_ + col]);
            const float pre = tanhf(accH[ni][reg] + eWh[(size_t)xr * H_ + col]);
            const float hv = (1.0f - z) * shF[r][col] + z * pre;
            h_t[(size_t)(e0 + r) * H_ + col] = hv;
            hB[r][col] = f2bf(hv);
        }
    }

    if (!do_ur) return;
    __syncthreads();

    // ---- MFMA phase 2: u_t = h_t @ Ur ----
    f32x4 accU[4];
#pragma unroll
    for (int i = 0; i < 4; ++i) accU[i] = (f32x4)(0.0f);

#pragma unroll
    for (int k0 = 0; k0 < H_; k0 += 32) {
        const bf16x8 a = *(const bf16x8*)&hB[c][k0 + kq];
#pragma unroll
        for (int ni = 0; ni < 4; ++ni) {
            const bf16x8 b = *(const bf16x8*)(Urt + (size_t)(n0 + ni * 16 + c) * H_ + k0 + kq);
            accU[ni] = __builtin_amdgcn_mfma_f32_16x16x32_bf16(a, b, accU[ni], 0, 0, 0);
        }
    }

    float* u_t = u + (size_t)(1 + t * E_) * H_;
#pragma unroll
    for (int reg = 0; reg < 4; ++reg) {
        const int r = quad * 4 + reg;
#pragma unroll
        for (int ni = 0; ni < 4; ++ni) {
            const int col = n0 + ni * 16 + c;
            u_t[(size_t)(e0 + r) * H_ + col] = accU[ni][reg];
        }
    }
}

// root_vecs[b] = relu(eWo[root_wid[b]] + sum_nei @ Wo_bot)   (eWo includes bo)
__global__ __launch_bounds__(256) void k_root(
    const int* __restrict__ root_wid, const int* __restrict__ root_nei,
    const float* __restrict__ h, const float* __restrict__ eWo,
    const float* __restrict__ Wo, float* __restrict__ out)
{
    const int b = blockIdx.x, d = threadIdx.x;
    __shared__ float sn[H_];
    __shared__ int idx[NB_];
    if (d < NB_) idx[d] = root_nei[b * NB_ + d];
    __syncthreads();
    float s = 0.0f;
#pragma unroll
    for (int j = 0; j < NB_; ++j) s += h[(size_t)idx[j] * H_ + d];
    sn[d] = s;
    __syncthreads();
    float acc = eWo[(size_t)root_wid[b] * H_ + d];
    for (int k = 0; k < H_; ++k)
        acc = fmaf(sn[k], Wo[(size_t)(H_ + k) * H_ + d], acc);
    out[(size_t)b * H_ + d] = fmaxf(acc, 0.0f);
}

extern "C" void kernel_launch(void* const* d_in, const int* in_sizes, int n_in,
                              void* d_out, int out_size, void* d_ws, size_t ws_size,
                              hipStream_t stream)
{
    const int*   x_ids    = (const int*)d_in[0];
    const int*   nei_idx  = (const int*)d_in[1];
    const int*   root_wid = (const int*)d_in[2];
    const int*   root_nei = (const int*)d_in[3];
    const float* emb      = (const float*)d_in[4];
    const float* Wz       = (const float*)d_in[5];
    const float* bz       = (const float*)d_in[6];
    const float* Wr       = (const float*)d_in[7];
    const float* Ur       = (const float*)d_in[8];
    const float* bur      = (const float*)d_in[9];
    const float* Wh       = (const float*)d_in[10];
    const float* bh       = (const float*)d_in[11];
    const float* Wo       = (const float*)d_in[12];
    const float* bo       = (const float*)d_in[13];

    float* h        = (float*)d_out;                      // [(1+M), H]
    float* root_out = h + (size_t)(1 + M_) * H_;          // [B, H]

    float* u    = (float*)d_ws;                           // [(1+M), H]  h @ Ur
    float* eWr  = u    + (size_t)(1 + M_) * H_;           // [V, H] emb@Wr + bur
    float* eWz  = eWr  + (size_t)V_ * H_;                 // [V, H] emb@Wz_top + bz
    float* eWh  = eWz  + (size_t)V_ * H_;                 // [V, H] emb@Wh_top + bh
    float* eWo  = eWh  + (size_t)V_ * H_;                 // [V, H] emb@Wo_top + bo
    short* Wzt  = (short*)(eWo + (size_t)V_ * H_);        // [256,256] bf16, transposed
    short* Wht  = Wzt + 65536;
    short* Urt  = Wht + 65536;

    const dim3 blk(256);

    k_init<<<dim3(1), blk, 0, stream>>>(h, u);
    k_wconv<<<dim3(768), blk, 0, stream>>>(Wz, Wh, Ur, Wzt, Wht, Urt);
    gemm_pre<<<dim3((V_ + 63) / 64, 4, 4), blk, 0, stream>>>(
        emb, Wr, Wz, Wh, Wo, bur, bz, bh, bo, eWr, eWz, eWh, eWo);

    for (int t = 0; t < T_; ++t) {
        k_step<<<dim3(E_ / TM), blk, 0, stream>>>(
            t, x_ids, nei_idx, h, u, eWr, eWz, eWh, Wzt, Wht, Urt,
            (t < T_ - 1) ? 1 : 0);
    }

    k_root<<<dim3(B_), blk, 0, stream>>>(root_wid, root_nei, h, eWo, Wo, root_out);
}

// Round 4
// 697.265 us; speedup vs baseline: 1.8695x; 1.2149x over previous
//
#include <hip/hip_runtime.h>
#include <hip/hip_bf16.h>
#include <math.h>

#define T_ 12
#define E_ 8192
#define H_ 256
#define V_ 800
#define B_ 256
#define NB_ 8
#define M_ (T_*E_)
#define TM 16            // message rows per k_step block
#define HP (H_ + 8)      // bf16 LDS row pad (keeps 16B alignment: 264*2=528B rows)

typedef __attribute__((ext_vector_type(8))) short bf16x8;
typedef __attribute__((ext_vector_type(4))) float f32x4;

__device__ __forceinline__ float sigmoidf_(float x) {
    return 1.0f / (1.0f + expf(-x));
}

// RNE f32 -> bf16 bits
__device__ __forceinline__ short f2bf(float x) {
    unsigned u = __float_as_uint(x);
    unsigned r = (u + 0x7fffu + ((u >> 16) & 1u)) >> 16;
    return (short)r;
}
__device__ __forceinline__ float bf2f(unsigned short s) {
    return __uint_as_float(((unsigned)s) << 16);
}

// Zero padding row (slot 0) of h (f32) and u (bf16). ws/out poisoned 0xAA each call.
__global__ __launch_bounds__(256) void k_init(float* __restrict__ h, unsigned short* __restrict__ u_bf) {
    int d = threadIdx.x;
    h[d] = 0.0f;
    u_bf[d] = 0;
}

// Weight prep: Wzt[n][k] = Wz[256+k][n], Wht[n][k] = Wh[256+k][n], Urt[n][k] = Ur[k][n], bf16.
__global__ __launch_bounds__(256) void k_wconv(
    const float* __restrict__ Wz, const float* __restrict__ Wh, const float* __restrict__ Ur,
    short* __restrict__ Wzt, short* __restrict__ Wht, short* __restrict__ Urt)
{
    int tid = blockIdx.x * 256 + threadIdx.x;
    int w = tid >> 16;
    int idx = tid & 65535;
    int n = idx >> 8, k = idx & 255;
    if (w == 0)      Wzt[idx] = f2bf(Wz[(size_t)(256 + k) * H_ + n]);
    else if (w == 1) Wht[idx] = f2bf(Wh[(size_t)(256 + k) * H_ + n]);
    else             Urt[idx] = f2bf(Ur[(size_t)k * H_ + n]);
}

// Batched prelude: eW*[v] = emb[v] @ Btop + bias  (blockIdx.z selects table)
__global__ __launch_bounds__(256) void gemm_pre(
    const float* __restrict__ emb,
    const float* __restrict__ Wr, const float* __restrict__ Wz,
    const float* __restrict__ Wh, const float* __restrict__ Wo,
    const float* __restrict__ bur, const float* __restrict__ bz,
    const float* __restrict__ bh, const float* __restrict__ bo,
    float* __restrict__ eWr, float* __restrict__ eWz,
    float* __restrict__ eWh, float* __restrict__ eWo)
{
    const float* Bm; const float* bias; float* C;
    switch (blockIdx.z) {
        case 0: Bm = Wr; bias = bur; C = eWr; break;
        case 1: Bm = Wz; bias = bz;  C = eWz; break;
        case 2: Bm = Wh; bias = bh;  C = eWh; break;
        default: Bm = Wo; bias = bo; C = eWo; break;
    }
    __shared__ float As[16][64];
    __shared__ float Bs[16][64];
    const int tid = threadIdx.x;
    const int bm = blockIdx.x * 64;
    const int bn = blockIdx.y * 64;
    const int a_m = tid & 63;
    const int a_k = (tid >> 6) << 2;
    const int b_k = tid >> 4;
    const int b_n = (tid & 15) << 2;
    const int tx = tid & 15, ty = tid >> 4;

    float acc[4][4] = {};
    const bool a_ok = (bm + a_m) < V_;
    const float* Ap = emb + (size_t)(bm + a_m) * H_ + a_k;
    const float* Bp = Bm + (size_t)b_k * H_ + bn + b_n;

    for (int k0 = 0; k0 < H_; k0 += 16) {
        float4 av = a_ok ? *(const float4*)(Ap + k0) : make_float4(0.f, 0.f, 0.f, 0.f);
        float4 bv = *(const float4*)(Bp + (size_t)k0 * H_);
        __syncthreads();
        As[a_k + 0][a_m] = av.x;
        As[a_k + 1][a_m] = av.y;
        As[a_k + 2][a_m] = av.z;
        As[a_k + 3][a_m] = av.w;
        *(float4*)&Bs[b_k][b_n] = bv;
        __syncthreads();
#pragma unroll
        for (int k = 0; k < 16; ++k) {
            const float4 a4 = *(const float4*)&As[k][ty << 2];
            const float4 b4 = *(const float4*)&Bs[k][tx << 2];
            const float ar[4] = {a4.x, a4.y, a4.z, a4.w};
            const float br[4] = {b4.x, b4.y, b4.z, b4.w};
#pragma unroll
            for (int i = 0; i < 4; ++i)
#pragma unroll
                for (int j = 0; j < 4; ++j)
                    acc[i][j] = fmaf(ar[i], br[j], acc[i][j]);
        }
    }

    const int col = bn + (tx << 2);
#pragma unroll
    for (int i = 0; i < 4; ++i) {
        const int row = bm + (ty << 2) + i;
        if (row >= V_) break;
        *(float4*)(C + (size_t)row * H_ + col) =
            make_float4(acc[i][0] + bias[col], acc[i][1] + bias[col + 1],
                        acc[i][2] + bias[col + 2], acc[i][3] + bias[col + 3]);
    }
}

// Fused step, 512 threads (8 waves): gather -> split Z/H MFMA -> epilogue -> Ur MFMA.
// Tables eWr/eWz/eWh include biases. u is stored bf16 (consumed only inside sigmoid).
__global__ __launch_bounds__(512, 4) void k_step(
    int t,
    const int* __restrict__ x_ids, const int* __restrict__ nei_idx,
    float* __restrict__ h, unsigned short* __restrict__ u_bf,
    const float* __restrict__ eWr, const float* __restrict__ eWz,
    const float* __restrict__ eWh,
    const short* __restrict__ Wzt, const short* __restrict__ Wht,
    const short* __restrict__ Urt,
    int do_ur)
{
    __shared__ int   idx[TM][NB_];
    __shared__ int   xw[TM];
    __shared__ float shF[TM][H_];   // sumh fp32 (epilogue)
    __shared__ short shB[TM][HP];   // sumh bf16 (A-frag, Z GEMM)
    __shared__ short sgB[TM][HP];   // sumg bf16 (A-frag, H GEMM)
    __shared__ short hB[TM][HP];    // h_t bf16 (A-frag, Ur GEMM)
    __shared__ float P[2][TM][H_];  // Z / H pre-activation GEMM results

    const int tid = threadIdx.x;
    const int e0 = blockIdx.x * TM;

    if (tid < TM * NB_) {
        int r = tid >> 3, j = tid & 7;
        idx[r][j] = nei_idx[((size_t)t * E_ + e0 + r) * NB_ + j];
    }
    if (tid < TM) xw[tid] = x_ids[t * E_ + e0 + tid];
    __syncthreads();

    // ---- gather: thread = (col, row-half); 8 rows x 8 neighbors each ----
    {
        const int c = tid & 255;
        const int r0 = (tid >> 8) * 8;
#pragma unroll 2
        for (int rr = 0; rr < 8; ++rr) {
            const int r = r0 + rr;
            const float r1 = eWr[(size_t)xw[r] * H_ + c];   // includes bur
            float sh = 0.0f, sg = 0.0f;
#pragma unroll
            for (int j = 0; j < NB_; ++j) {
                const size_t off = (size_t)idx[r][j] * H_ + c;
                const float hv = h[off];
                const float uv = bf2f(u_bf[off]);
                sh += hv;
                sg = fmaf(sigmoidf_(r1 + uv), hv, sg);
            }
            shF[r][c] = sh;
            shB[r][c] = f2bf(sh);
            sgB[r][c] = f2bf(sg);
        }
    }
    __syncthreads();

    // ---- MFMA: waves 0-3 -> P[0] = sumh @ WzBot; waves 4-7 -> P[1] = sumg @ WhBot ----
    const int lane = tid & 63;
    const int wave = tid >> 6;           // 0..7
    const int g = wave >> 2;             // 0: Z, 1: H
    const int n0 = (wave & 3) * 64;
    const int quad = lane >> 4, c = lane & 15;
    const int kq = quad * 8;

    {
        const short* Bt = g ? Wht : Wzt;
        const short (*Asrc)[HP] = g ? sgB : shB;
        f32x4 acc[4];
#pragma unroll
        for (int i = 0; i < 4; ++i) acc[i] = (f32x4)(0.0f);
#pragma unroll
        for (int k0 = 0; k0 < H_; k0 += 32) {
            const bf16x8 a = *(const bf16x8*)&Asrc[c][k0 + kq];
#pragma unroll
            for (int ni = 0; ni < 4; ++ni) {
                const bf16x8 b = *(const bf16x8*)(Bt + (size_t)(n0 + ni * 16 + c) * H_ + k0 + kq);
                acc[ni] = __builtin_amdgcn_mfma_f32_16x16x32_bf16(a, b, acc[ni], 0, 0, 0);
            }
        }
#pragma unroll
        for (int reg = 0; reg < 4; ++reg) {
            const int r = quad * 4 + reg;
#pragma unroll
            for (int ni = 0; ni < 4; ++ni)
                P[g][r][n0 + ni * 16 + c] = acc[ni][reg];
        }
    }
    __syncthreads();

    // ---- epilogue: h_t = (1-z)*sumh + z*pre ----
    float* h_t = h + (size_t)(1 + t * E_) * H_;
    {
        const int col = tid & 255;
        const int r0 = (tid >> 8) * 8;
#pragma unroll 2
        for (int rr = 0; rr < 8; ++rr) {
            const int r = r0 + rr;
            const int xr = xw[r];
            const float z   = sigmoidf_(P[0][r][col] + eWz[(size_t)xr * H_ + col]);
            const float pre = tanhf(P[1][r][col] + eWh[(size_t)xr * H_ + col]);
            const float hv = (1.0f - z) * shF[r][col] + z * pre;
            h_t[(size_t)(e0 + r) * H_ + col] = hv;
            hB[r][col] = f2bf(hv);
        }
    }

    if (!do_ur) return;
    __syncthreads();

    // ---- Ur MFMA: u_t = h_t @ Ur, 8 waves x 32 cols, bf16 store ----
    {
        const int n0u = wave * 32;
        f32x4 accU[2];
        accU[0] = (f32x4)(0.0f); accU[1] = (f32x4)(0.0f);
#pragma unroll
        for (int k0 = 0; k0 < H_; k0 += 32) {
            const bf16x8 a = *(const bf16x8*)&hB[c][k0 + kq];
#pragma unroll
            for (int ni = 0; ni < 2; ++ni) {
                const bf16x8 b = *(const bf16x8*)(Urt + (size_t)(n0u + ni * 16 + c) * H_ + k0 + kq);
                accU[ni] = __builtin_amdgcn_mfma_f32_16x16x32_bf16(a, b, accU[ni], 0, 0, 0);
            }
        }
        unsigned short* u_t = u_bf + (size_t)(1 + t * E_) * H_;
#pragma unroll
        for (int reg = 0; reg < 4; ++reg) {
            const int r = quad * 4 + reg;
#pragma unroll
            for (int ni = 0; ni < 2; ++ni)
                u_t[(size_t)(e0 + r) * H_ + n0u + ni * 16 + c] = (unsigned short)f2bf(accU[ni][reg]);
        }
    }
}

// root_vecs[b] = relu(eWo[root_wid[b]] + sum_nei @ Wo_bot)   (eWo includes bo)
__global__ __launch_bounds__(256) void k_root(
    const int* __restrict__ root_wid, const int* __restrict__ root_nei,
    const float* __restrict__ h, const float* __restrict__ eWo,
    const float* __restrict__ Wo, float* __restrict__ out)
{
    const int b = blockIdx.x, d = threadIdx.x;
    __shared__ float sn[H_];
    __shared__ int idx[NB_];
    if (d < NB_) idx[d] = root_nei[b * NB_ + d];
    __syncthreads();
    float s = 0.0f;
#pragma unroll
    for (int j = 0; j < NB_; ++j) s += h[(size_t)idx[j] * H_ + d];
    sn[d] = s;
    __syncthreads();
    float acc = eWo[(size_t)root_wid[b] * H_ + d];
    for (int k = 0; k < H_; ++k)
        acc = fmaf(sn[k], Wo[(size_t)(H_ + k) * H_ + d], acc);
    out[(size_t)b * H_ + d] = fmaxf(acc, 0.0f);
}

extern "C" void kernel_launch(void* const* d_in, const int* in_sizes, int n_in,
                              void* d_out, int out_size, void* d_ws, size_t ws_size,
                              hipStream_t stream)
{
    const int*   x_ids    = (const int*)d_in[0];
    const int*   nei_idx  = (const int*)d_in[1];
    const int*   root_wid = (const int*)d_in[2];
    const int*   root_nei = (const int*)d_in[3];
    const float* emb      = (const float*)d_in[4];
    const float* Wz       = (const float*)d_in[5];
    const float* bz       = (const float*)d_in[6];
    const float* Wr       = (const float*)d_in[7];
    const float* Ur       = (const float*)d_in[8];
    const float* bur      = (const float*)d_in[9];
    const float* Wh       = (const float*)d_in[10];
    const float* bh       = (const float*)d_in[11];
    const float* Wo       = (const float*)d_in[12];
    const float* bo       = (const float*)d_in[13];

    float* h        = (float*)d_out;                      // [(1+M), H]
    float* root_out = h + (size_t)(1 + M_) * H_;          // [B, H]

    unsigned short* u_bf = (unsigned short*)d_ws;         // [(1+M), H]  (h @ Ur) in bf16
    float* eWr  = (float*)(u_bf + (size_t)(1 + M_) * H_); // [V, H] emb@Wr + bur
    float* eWz  = eWr  + (size_t)V_ * H_;                 // [V, H] emb@Wz_top + bz
    float* eWh  = eWz  + (size_t)V_ * H_;                 // [V, H] emb@Wh_top + bh
    float* eWo  = eWh  + (size_t)V_ * H_;                 // [V, H] emb@Wo_top + bo
    short* Wzt  = (short*)(eWo + (size_t)V_ * H_);        // [256,256] bf16 transposed
    short* Wht  = Wzt + 65536;
    short* Urt  = Wht + 65536;

    k_init<<<dim3(1), dim3(256), 0, stream>>>(h, u_bf);
    k_wconv<<<dim3(768), dim3(256), 0, stream>>>(Wz, Wh, Ur, Wzt, Wht, Urt);
    gemm_pre<<<dim3((V_ + 63) / 64, 4, 4), dim3(256), 0, stream>>>(
        emb, Wr, Wz, Wh, Wo, bur, bz, bh, bo, eWr, eWz, eWh, eWo);

    for (int t = 0; t < T_; ++t) {
        k_step<<<dim3(E_ / TM), dim3(512), 0, stream>>>(
            t, x_ids, nei_idx, h, u_bf, eWr, eWz, eWh, Wzt, Wht, Urt,
            (t < T_ - 1) ? 1 : 0);
    }

    k_root<<<dim3(B_), dim3(256), 0, stream>>>(root_wid, root_nei, h, eWo, Wo, root_out);
}

// Round 5
// 656.594 us; speedup vs baseline: 1.9853x; 1.0619x over previous
//
#include <hip/hip_runtime.h>
#include <hip/hip_bf16.h>
#include <math.h>

#define T_ 12
#define E_ 8192
#define H_ 256
#define V_ 800
#define B_ 256
#define NB_ 8
#define M_ (T_*E_)
#define TM 16            // message rows per k_step block
#define HP (H_ + 8)      // bf16 LDS row pad

typedef __attribute__((ext_vector_type(8))) short bf16x8;
typedef __attribute__((ext_vector_type(4))) float f32x4;

__device__ __forceinline__ float sigmoidf_(float x) {
    return 1.0f / (1.0f + expf(-x));
}

// RNE f32 -> bf16 bits
__device__ __forceinline__ short f2bf(float x) {
    unsigned u = __float_as_uint(x);
    unsigned r = (u + 0x7fffu + ((u >> 16) & 1u)) >> 16;
    return (short)r;
}
// packed hu word: lo16 = h bf16, hi16 = u bf16
__device__ __forceinline__ float hu_h(unsigned v) { return __uint_as_float(v << 16); }
__device__ __forceinline__ float hu_u(unsigned v) { return __uint_as_float(v & 0xffff0000u); }

// Zero padding row (slot 0) of h (f32) and hu (packed). ws/out poisoned 0xAA each call.
__global__ __launch_bounds__(256) void k_init(float* __restrict__ h, unsigned* __restrict__ hu) {
    int d = threadIdx.x;
    h[d] = 0.0f;
    hu[d] = 0u;
}

// Weight prep: Wzt[n][k] = Wz[256+k][n], Wht[n][k] = Wh[256+k][n], Urt[n][k] = Ur[k][n], bf16.
__global__ __launch_bounds__(256) void k_wconv(
    const float* __restrict__ Wz, const float* __restrict__ Wh, const float* __restrict__ Ur,
    short* __restrict__ Wzt, short* __restrict__ Wht, short* __restrict__ Urt)
{
    int tid = blockIdx.x * 256 + threadIdx.x;
    int w = tid >> 16;
    int idx = tid & 65535;
    int n = idx >> 8, k = idx & 255;
    if (w == 0)      Wzt[idx] = f2bf(Wz[(size_t)(256 + k) * H_ + n]);
    else if (w == 1) Wht[idx] = f2bf(Wh[(size_t)(256 + k) * H_ + n]);
    else             Urt[idx] = f2bf(Ur[(size_t)k * H_ + n]);
}

// Batched prelude: eW*[v] = emb[v] @ Btop + bias  (blockIdx.z selects table)
__global__ __launch_bounds__(256) void gemm_pre(
    const float* __restrict__ emb,
    const float* __restrict__ Wr, const float* __restrict__ Wz,
    const float* __restrict__ Wh, const float* __restrict__ Wo,
    const float* __restrict__ bur, const float* __restrict__ bz,
    const float* __restrict__ bh, const float* __restrict__ bo,
    float* __restrict__ eWr, float* __restrict__ eWz,
    float* __restrict__ eWh, float* __restrict__ eWo)
{
    const float* Bm; const float* bias; float* C;
    switch (blockIdx.z) {
        case 0: Bm = Wr; bias = bur; C = eWr; break;
        case 1: Bm = Wz; bias = bz;  C = eWz; break;
        case 2: Bm = Wh; bias = bh;  C = eWh; break;
        default: Bm = Wo; bias = bo; C = eWo; break;
    }
    __shared__ float As[16][64];
    __shared__ float Bs[16][64];
    const int tid = threadIdx.x;
    const int bm = blockIdx.x * 64;
    const int bn = blockIdx.y * 64;
    const int a_m = tid & 63;
    const int a_k = (tid >> 6) << 2;
    const int b_k = tid >> 4;
    const int b_n = (tid & 15) << 2;
    const int tx = tid & 15, ty = tid >> 4;

    float acc[4][4] = {};
    const bool a_ok = (bm + a_m) < V_;
    const float* Ap = emb + (size_t)(bm + a_m) * H_ + a_k;
    const float* Bp = Bm + (size_t)b_k * H_ + bn + b_n;

    for (int k0 = 0; k0 < H_; k0 += 16) {
        float4 av = a_ok ? *(const float4*)(Ap + k0) : make_float4(0.f, 0.f, 0.f, 0.f);
        float4 bv = *(const float4*)(Bp + (size_t)k0 * H_);
        __syncthreads();
        As[a_k + 0][a_m] = av.x;
        As[a_k + 1][a_m] = av.y;
        As[a_k + 2][a_m] = av.z;
        As[a_k + 3][a_m] = av.w;
        *(float4*)&Bs[b_k][b_n] = bv;
        __syncthreads();
#pragma unroll
        for (int k = 0; k < 16; ++k) {
            const float4 a4 = *(const float4*)&As[k][ty << 2];
            const float4 b4 = *(const float4*)&Bs[k][tx << 2];
            const float ar[4] = {a4.x, a4.y, a4.z, a4.w};
            const float br[4] = {b4.x, b4.y, b4.z, b4.w};
#pragma unroll
            for (int i = 0; i < 4; ++i)
#pragma unroll
                for (int j = 0; j < 4; ++j)
                    acc[i][j] = fmaf(ar[i], br[j], acc[i][j]);
        }
    }

    const int col = bn + (tx << 2);
#pragma unroll
    for (int i = 0; i < 4; ++i) {
        const int row = bm + (ty << 2) + i;
        if (row >= V_) break;
        *(float4*)(C + (size_t)row * H_ + col) =
            make_float4(acc[i][0] + bias[col], acc[i][1] + bias[col + 1],
                        acc[i][2] + bias[col + 2], acc[i][3] + bias[col + 3]);
    }
}

// Fused step, 512 threads (8 waves): batched packed gather -> split Z/H MFMA ->
// epilogue -> Ur MFMA (+ packed hu store). Tables eWr/eWz/eWh include biases.
__global__ __launch_bounds__(512, 4) void k_step(
    int t,
    const int* __restrict__ x_ids, const int* __restrict__ nei_idx,
    float* __restrict__ h, unsigned* __restrict__ hu,
    const float* __restrict__ eWr, const float* __restrict__ eWz,
    const float* __restrict__ eWh,
    const short* __restrict__ Wzt, const short* __restrict__ Wht,
    const short* __restrict__ Urt,
    int do_ur)
{
    __shared__ int   idx[TM][NB_];
    __shared__ int   xw[TM];
    __shared__ float shF[TM][H_];   // sumh fp32 (epilogue)
    __shared__ short shB[TM][HP];   // sumh bf16 (A-frag, Z GEMM)
    __shared__ short sgB[TM][HP];   // sumg bf16 (A-frag, H GEMM)
    __shared__ short hB[TM][HP];    // h_t bf16 (A-frag, Ur GEMM + hu pack)
    __shared__ float P[2][TM][H_];  // Z / H pre-activation GEMM results

    const int tid = threadIdx.x;
    const int e0 = blockIdx.x * TM;

    if (tid < TM * NB_) {
        int r = tid >> 3, j = tid & 7;
        idx[r][j] = nei_idx[((size_t)t * E_ + e0 + r) * NB_ + j];
    }
    if (tid < TM) xw[tid] = x_ids[t * E_ + e0 + tid];
    __syncthreads();

    // ---- gather: thread = (col, row-half); 2 rows batched -> 16 loads in flight ----
    {
        const int c = tid & 255;
        const int r0 = (tid >> 8) * 8;
        for (int rr = 0; rr < 8; rr += 2) {
            const int ra = r0 + rr, rb = ra + 1;
            unsigned va[NB_], vb[NB_];
#pragma unroll
            for (int j = 0; j < NB_; ++j)
                va[j] = hu[(size_t)idx[ra][j] * H_ + c];
#pragma unroll
            for (int j = 0; j < NB_; ++j)
                vb[j] = hu[(size_t)idx[rb][j] * H_ + c];

            const float r1a = eWr[(size_t)xw[ra] * H_ + c];   // includes bur
            const float r1b = eWr[(size_t)xw[rb] * H_ + c];
            float sha = 0.f, sga = 0.f, shb = 0.f, sgb = 0.f;
#pragma unroll
            for (int j = 0; j < NB_; ++j) {
                const float hva = hu_h(va[j]);
                sha += hva;
                sga = fmaf(sigmoidf_(r1a + hu_u(va[j])), hva, sga);
                const float hvb = hu_h(vb[j]);
                shb += hvb;
                sgb = fmaf(sigmoidf_(r1b + hu_u(vb[j])), hvb, sgb);
            }
            shF[ra][c] = sha; shB[ra][c] = f2bf(sha); sgB[ra][c] = f2bf(sga);
            shF[rb][c] = shb; shB[rb][c] = f2bf(shb); sgB[rb][c] = f2bf(sgb);
        }
    }
    __syncthreads();

    // ---- MFMA: waves 0-3 -> P[0] = sumh @ WzBot; waves 4-7 -> P[1] = sumg @ WhBot ----
    const int lane = tid & 63;
    const int wave = tid >> 6;           // 0..7
    const int g = wave >> 2;             // 0: Z, 1: H
    const int n0 = (wave & 3) * 64;
    const int quad = lane >> 4, c = lane & 15;
    const int kq = quad * 8;

    {
        const short* Bt = g ? Wht : Wzt;
        const short (*Asrc)[HP] = g ? sgB : shB;
        f32x4 acc[4];
#pragma unroll
        for (int i = 0; i < 4; ++i) acc[i] = (f32x4)(0.0f);
#pragma unroll
        for (int k0 = 0; k0 < H_; k0 += 32) {
            const bf16x8 a = *(const bf16x8*)&Asrc[c][k0 + kq];
#pragma unroll
            for (int ni = 0; ni < 4; ++ni) {
                const bf16x8 b = *(const bf16x8*)(Bt + (size_t)(n0 + ni * 16 + c) * H_ + k0 + kq);
                acc[ni] = __builtin_amdgcn_mfma_f32_16x16x32_bf16(a, b, acc[ni], 0, 0, 0);
            }
        }
#pragma unroll
        for (int reg = 0; reg < 4; ++reg) {
            const int r = quad * 4 + reg;
#pragma unroll
            for (int ni = 0; ni < 4; ++ni)
                P[g][r][n0 + ni * 16 + c] = acc[ni][reg];
        }
    }
    __syncthreads();

    // ---- epilogue: h_t = (1-z)*sumh + z*pre ----
    float* h_t = h + (size_t)(1 + t * E_) * H_;
    {
        const int col = tid & 255;
        const int r0 = (tid >> 8) * 8;
#pragma unroll 2
        for (int rr = 0; rr < 8; ++rr) {
            const int r = r0 + rr;
            const int xr = xw[r];
            const float z   = sigmoidf_(P[0][r][col] + eWz[(size_t)xr * H_ + col]);
            const float pre = tanhf(P[1][r][col] + eWh[(size_t)xr * H_ + col]);
            const float hv = (1.0f - z) * shF[r][col] + z * pre;
            h_t[(size_t)(e0 + r) * H_ + col] = hv;
            hB[r][col] = f2bf(hv);
        }
    }

    if (!do_ur) return;
    __syncthreads();

    // ---- Ur MFMA: u = h_t @ Ur; store packed {h_bf16, u_bf16} ----
    {
        const int n0u = wave * 32;
        f32x4 accU[2];
        accU[0] = (f32x4)(0.0f); accU[1] = (f32x4)(0.0f);
#pragma unroll
        for (int k0 = 0; k0 < H_; k0 += 32) {
            const bf16x8 a = *(const bf16x8*)&hB[c][k0 + kq];
#pragma unroll
            for (int ni = 0; ni < 2; ++ni) {
                const bf16x8 b = *(const bf16x8*)(Urt + (size_t)(n0u + ni * 16 + c) * H_ + k0 + kq);
                accU[ni] = __builtin_amdgcn_mfma_f32_16x16x32_bf16(a, b, accU[ni], 0, 0, 0);
            }
        }
        unsigned* hu_t = hu + (size_t)(1 + t * E_) * H_;
#pragma unroll
        for (int reg = 0; reg < 4; ++reg) {
            const int r = quad * 4 + reg;
#pragma unroll
            for (int ni = 0; ni < 2; ++ni) {
                const int col = n0u + ni * 16 + c;
                const unsigned ubits = (unsigned)(unsigned short)f2bf(accU[ni][reg]);
                const unsigned hbits = (unsigned)(unsigned short)hB[r][col];
                hu_t[(size_t)(e0 + r) * H_ + col] = (ubits << 16) | hbits;
            }
        }
    }
}

// root_vecs[b] = relu(eWo[root_wid[b]] + sum_nei @ Wo_bot)   (eWo includes bo)
__global__ __launch_bounds__(256) void k_root(
    const int* __restrict__ root_wid, const int* __restrict__ root_nei,
    const float* __restrict__ h, const float* __restrict__ eWo,
    const float* __restrict__ Wo, float* __restrict__ out)
{
    const int b = blockIdx.x, d = threadIdx.x;
    __shared__ float sn[H_];
    __shared__ int idx[NB_];
    if (d < NB_) idx[d] = root_nei[b * NB_ + d];
    __syncthreads();
    float s = 0.0f;
#pragma unroll
    for (int j = 0; j < NB_; ++j) s += h[(size_t)idx[j] * H_ + d];
    sn[d] = s;
    __syncthreads();
    float acc = eWo[(size_t)root_wid[b] * H_ + d];
    for (int k = 0; k < H_; ++k)
        acc = fmaf(sn[k], Wo[(size_t)(H_ + k) * H_ + d], acc);
    out[(size_t)b * H_ + d] = fmaxf(acc, 0.0f);
}

extern "C" void kernel_launch(void* const* d_in, const int* in_sizes, int n_in,
                              void* d_out, int out_size, void* d_ws, size_t ws_size,
                              hipStream_t stream)
{
    const int*   x_ids    = (const int*)d_in[0];
    const int*   nei_idx  = (const int*)d_in[1];
    const int*   root_wid = (const int*)d_in[2];
    const int*   root_nei = (const int*)d_in[3];
    const float* emb      = (const float*)d_in[4];
    const float* Wz       = (const float*)d_in[5];
    const float* bz       = (const float*)d_in[6];
    const float* Wr       = (const float*)d_in[7];
    const float* Ur       = (const float*)d_in[8];
    const float* bur      = (const float*)d_in[9];
    const float* Wh       = (const float*)d_in[10];
    const float* bh       = (const float*)d_in[11];
    const float* Wo       = (const float*)d_in[12];
    const float* bo       = (const float*)d_in[13];

    float* h        = (float*)d_out;                      // [(1+M), H]
    float* root_out = h + (size_t)(1 + M_) * H_;          // [B, H]

    unsigned* hu = (unsigned*)d_ws;                       // [(1+M), H] packed {h,u} bf16
    float* eWr  = (float*)(hu + (size_t)(1 + M_) * H_);   // [V, H] emb@Wr + bur
    float* eWz  = eWr  + (size_t)V_ * H_;                 // [V, H] emb@Wz_top + bz
    float* eWh  = eWz  + (size_t)V_ * H_;                 // [V, H] emb@Wh_top + bh
    float* eWo  = eWh  + (size_t)V_ * H_;                 // [V, H] emb@Wo_top + bo
    short* Wzt  = (short*)(eWo + (size_t)V_ * H_);        // [256,256] bf16 transposed
    short* Wht  = Wzt + 65536;
    short* Urt  = Wht + 65536;

    k_init<<<dim3(1), dim3(256), 0, stream>>>(h, hu);
    k_wconv<<<dim3(768), dim3(256), 0, stream>>>(Wz, Wh, Ur, Wzt, Wht, Urt);
    gemm_pre<<<dim3((V_ + 63) / 64, 4, 4), dim3(256), 0, stream>>>(
        emb, Wr, Wz, Wh, Wo, bur, bz, bh, bo, eWr, eWz, eWh, eWo);

    for (int t = 0; t < T_; ++t) {
        k_step<<<dim3(E_ / TM), dim3(512), 0, stream>>>(
            t, x_ids, nei_idx, h, hu, eWr, eWz, eWh, Wzt, Wht, Urt,
            (t < T_ - 1) ? 1 : 0);
    }

    k_root<<<dim3(B_), dim3(256), 0, stream>>>(root_wid, root_nei, h, eWo, Wo, root_out);
}

// Round 6
// 644.439 us; speedup vs baseline: 2.0227x; 1.0189x over previous
//
#include <hip/hip_runtime.h>
#include <hip/hip_bf16.h>
#include <math.h>

#define T_ 12
#define E_ 8192
#define H_ 256
#define V_ 800
#define B_ 256
#define NB_ 8
#define M_ (T_*E_)
#define TM 16            // message rows per k_step block
#define HP (H_ + 8)      // bf16 LDS row pad

typedef __attribute__((ext_vector_type(8))) short bf16x8;
typedef __attribute__((ext_vector_type(4))) float f32x4;

__device__ __forceinline__ float sigmoidf_(float x) {
    return 1.0f / (1.0f + expf(-x));
}

// RNE f32 -> bf16 bits
__device__ __forceinline__ short f2bf(float x) {
    unsigned u = __float_as_uint(x);
    unsigned r = (u + 0x7fffu + ((u >> 16) & 1u)) >> 16;
    return (short)r;
}
__device__ __forceinline__ float bf2f(unsigned short s) {
    return __uint_as_float(((unsigned)s) << 16);
}
// packed hu word: lo16 = h bf16, hi16 = u bf16
__device__ __forceinline__ float hu_h(unsigned v) { return __uint_as_float(v << 16); }
__device__ __forceinline__ float hu_u(unsigned v) { return __uint_as_float(v & 0xffff0000u); }

// Weight prep (+ slot-0 init folded into block 768).
// Wzt[n][k] = Wz[256+k][n], Wht[n][k] = Wh[256+k][n], Urt[n][k] = Ur[k][n], bf16.
__global__ __launch_bounds__(256) void k_wconv(
    const float* __restrict__ Wz, const float* __restrict__ Wh, const float* __restrict__ Ur,
    short* __restrict__ Wzt, short* __restrict__ Wht, short* __restrict__ Urt,
    float* __restrict__ h, unsigned* __restrict__ hu)
{
    if (blockIdx.x == 768) {            // zero padding row (slot 0) of h and hu
        h[threadIdx.x] = 0.0f;
        hu[threadIdx.x] = 0u;
        return;
    }
    int tid = blockIdx.x * 256 + threadIdx.x;
    int w = tid >> 16;
    int idx = tid & 65535;
    int n = idx >> 8, k = idx & 255;
    if (w == 0)      Wzt[idx] = f2bf(Wz[(size_t)(256 + k) * H_ + n]);
    else if (w == 1) Wht[idx] = f2bf(Wh[(size_t)(256 + k) * H_ + n]);
    else             Urt[idx] = f2bf(Ur[(size_t)k * H_ + n]);
}

// Batched prelude: eW*[v] = emb[v] @ Btop + bias  (blockIdx.z selects table)
__global__ __launch_bounds__(256) void gemm_pre(
    const float* __restrict__ emb,
    const float* __restrict__ Wr, const float* __restrict__ Wz,
    const float* __restrict__ Wh, const float* __restrict__ Wo,
    const float* __restrict__ bur, const float* __restrict__ bz,
    const float* __restrict__ bh, const float* __restrict__ bo,
    float* __restrict__ eWr, float* __restrict__ eWz,
    float* __restrict__ eWh, float* __restrict__ eWo)
{
    const float* Bm; const float* bias; float* C;
    switch (blockIdx.z) {
        case 0: Bm = Wr; bias = bur; C = eWr; break;
        case 1: Bm = Wz; bias = bz;  C = eWz; break;
        case 2: Bm = Wh; bias = bh;  C = eWh; break;
        default: Bm = Wo; bias = bo; C = eWo; break;
    }
    __shared__ float As[16][64];
    __shared__ float Bs[16][64];
    const int tid = threadIdx.x;
    const int bm = blockIdx.x * 64;
    const int bn = blockIdx.y * 64;
    const int a_m = tid & 63;
    const int a_k = (tid >> 6) << 2;
    const int b_k = tid >> 4;
    const int b_n = (tid & 15) << 2;
    const int tx = tid & 15, ty = tid >> 4;

    float acc[4][4] = {};
    const bool a_ok = (bm + a_m) < V_;
    const float* Ap = emb + (size_t)(bm + a_m) * H_ + a_k;
    const float* Bp = Bm + (size_t)b_k * H_ + bn + b_n;

    for (int k0 = 0; k0 < H_; k0 += 16) {
        float4 av = a_ok ? *(const float4*)(Ap + k0) : make_float4(0.f, 0.f, 0.f, 0.f);
        float4 bv = *(const float4*)(Bp + (size_t)k0 * H_);
        __syncthreads();
        As[a_k + 0][a_m] = av.x;
        As[a_k + 1][a_m] = av.y;
        As[a_k + 2][a_m] = av.z;
        As[a_k + 3][a_m] = av.w;
        *(float4*)&Bs[b_k][b_n] = bv;
        __syncthreads();
#pragma unroll
        for (int k = 0; k < 16; ++k) {
            const float4 a4 = *(const float4*)&As[k][ty << 2];
            const float4 b4 = *(const float4*)&Bs[k][tx << 2];
            const float ar[4] = {a4.x, a4.y, a4.z, a4.w};
            const float br[4] = {b4.x, b4.y, b4.z, b4.w};
#pragma unroll
            for (int i = 0; i < 4; ++i)
#pragma unroll
                for (int j = 0; j < 4; ++j)
                    acc[i][j] = fmaf(ar[i], br[j], acc[i][j]);
        }
    }

    const int col = bn + (tx << 2);
#pragma unroll
    for (int i = 0; i < 4; ++i) {
        const int row = bm + (ty << 2) + i;
        if (row >= V_) break;
        *(float4*)(C + (size_t)row * H_ + col) =
            make_float4(acc[i][0] + bias[col], acc[i][1] + bias[col + 1],
                        acc[i][2] + bias[col + 2], acc[i][3] + bias[col + 3]);
    }
}

// Fused step, 512 threads (8 waves), 25.3 KB LDS -> 4 blocks/CU (32 waves/CU).
// Each wave owns a 32-col strip and computes BOTH Z and H accумs for it, so the
// epilogue is in-register (no LDS exchange). Tables eWr/eWz/eWh include biases.
__global__ __launch_bounds__(512, 8) void k_step(
    int t,
    const int* __restrict__ x_ids, const int* __restrict__ nei_idx,
    float* __restrict__ h, unsigned* __restrict__ hu,
    const float* __restrict__ eWr, const float* __restrict__ eWz,
    const float* __restrict__ eWh,
    const short* __restrict__ Wzt, const short* __restrict__ Wht,
    const short* __restrict__ Urt,
    int do_ur)
{
    __shared__ int   idx[TM][NB_];
    __shared__ int   xw[TM];
    __shared__ short shB[TM][HP];   // sumh bf16 (A-frag + epilogue linear term)
    __shared__ short sgB[TM][HP];   // sumg bf16 (A-frag)
    __shared__ short hB[TM][HP];    // h_t bf16 (A-frag Ur + hu pack)

    const int tid = threadIdx.x;
    const int e0 = blockIdx.x * TM;

    if (tid < TM * NB_) {
        int r = tid >> 3, j = tid & 7;
        idx[r][j] = nei_idx[((size_t)t * E_ + e0 + r) * NB_ + j];
    }
    if (tid < TM) xw[tid] = x_ids[t * E_ + e0 + tid];
    __syncthreads();

    // ---- gather: thread = (col, row-half); 2 rows batched -> 16 loads in flight ----
    {
        const int c = tid & 255;
        const int r0 = (tid >> 8) * 8;
        for (int rr = 0; rr < 8; rr += 2) {
            const int ra = r0 + rr, rb = ra + 1;
            unsigned va[NB_], vb[NB_];
#pragma unroll
            for (int j = 0; j < NB_; ++j)
                va[j] = hu[(size_t)idx[ra][j] * H_ + c];
#pragma unroll
            for (int j = 0; j < NB_; ++j)
                vb[j] = hu[(size_t)idx[rb][j] * H_ + c];

            const float r1a = eWr[(size_t)xw[ra] * H_ + c];   // includes bur
            const float r1b = eWr[(size_t)xw[rb] * H_ + c];
            float sha = 0.f, sga = 0.f, shb = 0.f, sgb = 0.f;
#pragma unroll
            for (int j = 0; j < NB_; ++j) {
                const float hva = hu_h(va[j]);
                sha += hva;
                sga = fmaf(sigmoidf_(r1a + hu_u(va[j])), hva, sga);
                const float hvb = hu_h(vb[j]);
                shb += hvb;
                sgb = fmaf(sigmoidf_(r1b + hu_u(vb[j])), hvb, sgb);
            }
            shB[ra][c] = f2bf(sha); sgB[ra][c] = f2bf(sga);
            shB[rb][c] = f2bf(shb); sgB[rb][c] = f2bf(sgb);
        }
    }
    __syncthreads();

    // ---- MFMA + in-register epilogue: wave owns 32-col strip, both Z and H ----
    const int lane = tid & 63;
    const int wave = tid >> 6;           // 0..7
    const int n0 = wave * 32;
    const int quad = lane >> 4, c = lane & 15;
    const int kq = quad * 8;

    f32x4 accZ[2], accH[2];
#pragma unroll
    for (int i = 0; i < 2; ++i) { accZ[i] = (f32x4)(0.0f); accH[i] = (f32x4)(0.0f); }

#pragma unroll
    for (int k0 = 0; k0 < H_; k0 += 32) {
        const bf16x8 a1 = *(const bf16x8*)&shB[c][k0 + kq];
        const bf16x8 a2 = *(const bf16x8*)&sgB[c][k0 + kq];
#pragma unroll
        for (int ni = 0; ni < 2; ++ni) {
            const size_t boff = (size_t)(n0 + ni * 16 + c) * H_ + k0 + kq;
            const bf16x8 b1 = *(const bf16x8*)(Wzt + boff);
            const bf16x8 b2 = *(const bf16x8*)(Wht + boff);
            accZ[ni] = __builtin_amdgcn_mfma_f32_16x16x32_bf16(a1, b1, accZ[ni], 0, 0, 0);
            accH[ni] = __builtin_amdgcn_mfma_f32_16x16x32_bf16(a2, b2, accH[ni], 0, 0, 0);
        }
    }

    // epilogue: h_t = (1-z)*sumh + z*pre, all in-register per C-cell
    float* h_t = h + (size_t)(1 + t * E_) * H_;
#pragma unroll
    for (int reg = 0; reg < 4; ++reg) {
        const int r = quad * 4 + reg;
        const int xr = xw[r];
#pragma unroll
        for (int ni = 0; ni < 2; ++ni) {
            const int col = n0 + ni * 16 + c;
            const float z   = sigmoidf_(accZ[ni][reg] + eWz[(size_t)xr * H_ + col]);
            const float pre = tanhf(accH[ni][reg] + eWh[(size_t)xr * H_ + col]);
            const float hv = (1.0f - z) * bf2f((unsigned short)shB[r][col]) + z * pre;
            h_t[(size_t)(e0 + r) * H_ + col] = hv;
            hB[r][col] = f2bf(hv);
        }
    }

    if (!do_ur) return;
    __syncthreads();

    // ---- Ur MFMA: u = h_t @ Ur; store packed {h_bf16, u_bf16} ----
    {
        f32x4 accU[2];
        accU[0] = (f32x4)(0.0f); accU[1] = (f32x4)(0.0f);
#pragma unroll
        for (int k0 = 0; k0 < H_; k0 += 32) {
            const bf16x8 a = *(const bf16x8*)&hB[c][k0 + kq];
#pragma unroll
            for (int ni = 0; ni < 2; ++ni) {
                const bf16x8 b = *(const bf16x8*)(Urt + (size_t)(n0 + ni * 16 + c) * H_ + k0 + kq);
                accU[ni] = __builtin_amdgcn_mfma_f32_16x16x32_bf16(a, b, accU[ni], 0, 0, 0);
            }
        }
        unsigned* hu_t = hu + (size_t)(1 + t * E_) * H_;
#pragma unroll
        for (int reg = 0; reg < 4; ++reg) {
            const int r = quad * 4 + reg;
#pragma unroll
            for (int ni = 0; ni < 2; ++ni) {
                const int col = n0 + ni * 16 + c;
                const unsigned ubits = (unsigned)(unsigned short)f2bf(accU[ni][reg]);
                const unsigned hbits = (unsigned)(unsigned short)hB[r][col];
                hu_t[(size_t)(e0 + r) * H_ + col] = (ubits << 16) | hbits;
            }
        }
    }
}

// root_vecs[b] = relu(eWo[root_wid[b]] + sum_nei @ Wo_bot)   (eWo includes bo)
__global__ __launch_bounds__(256) void k_root(
    const int* __restrict__ root_wid, const int* __restrict__ root_nei,
    const float* __restrict__ h, const float* __restrict__ eWo,
    const float* __restrict__ Wo, float* __restrict__ out)
{
    const int b = blockIdx.x, d = threadIdx.x;
    __shared__ float sn[H_];
    __shared__ int idx[NB_];
    if (d < NB_) idx[d] = root_nei[b * NB_ + d];
    __syncthreads();
    float s = 0.0f;
#pragma unroll
    for (int j = 0; j < NB_; ++j) s += h[(size_t)idx[j] * H_ + d];
    sn[d] = s;
    __syncthreads();
    float acc = eWo[(size_t)root_wid[b] * H_ + d];
    for (int k = 0; k < H_; ++k)
        acc = fmaf(sn[k], Wo[(size_t)(H_ + k) * H_ + d], acc);
    out[(size_t)b * H_ + d] = fmaxf(acc, 0.0f);
}

extern "C" void kernel_launch(void* const* d_in, const int* in_sizes, int n_in,
                              void* d_out, int out_size, void* d_ws, size_t ws_size,
                              hipStream_t stream)
{
    const int*   x_ids    = (const int*)d_in[0];
    const int*   nei_idx  = (const int*)d_in[1];
    const int*   root_wid = (const int*)d_in[2];
    const int*   root_nei = (const int*)d_in[3];
    const float* emb      = (const float*)d_in[4];
    const float* Wz       = (const float*)d_in[5];
    const float* bz       = (const float*)d_in[6];
    const float* Wr       = (const float*)d_in[7];
    const float* Ur       = (const float*)d_in[8];
    const float* bur      = (const float*)d_in[9];
    const float* Wh       = (const float*)d_in[10];
    const float* bh       = (const float*)d_in[11];
    const float* Wo       = (const float*)d_in[12];
    const float* bo       = (const float*)d_in[13];

    float* h        = (float*)d_out;                      // [(1+M), H]
    float* root_out = h + (size_t)(1 + M_) * H_;          // [B, H]

    unsigned* hu = (unsigned*)d_ws;                       // [(1+M), H] packed {h,u} bf16
    float* eWr  = (float*)(hu + (size_t)(1 + M_) * H_);   // [V, H] emb@Wr + bur
    float* eWz  = eWr  + (size_t)V_ * H_;                 // [V, H] emb@Wz_top + bz
    float* eWh  = eWz  + (size_t)V_ * H_;                 // [V, H] emb@Wh_top + bh
    float* eWo  = eWh  + (size_t)V_ * H_;                 // [V, H] emb@Wo_top + bo
    short* Wzt  = (short*)(eWo + (size_t)V_ * H_);        // [256,256] bf16 transposed
    short* Wht  = Wzt + 65536;
    short* Urt  = Wht + 65536;

    k_wconv<<<dim3(769), dim3(256), 0, stream>>>(Wz, Wh, Ur, Wzt, Wht, Urt, h, hu);
    gemm_pre<<<dim3((V_ + 63) / 64, 4, 4), dim3(256), 0, stream>>>(
        emb, Wr, Wz, Wh, Wo, bur, bz, bh, bo, eWr, eWz, eWh, eWo);

    for (int t = 0; t < T_; ++t) {
        k_step<<<dim3(E_ / TM), dim3(512), 0, stream>>>(
            t, x_ids, nei_idx, h, hu, eWr, eWz, eWh, Wzt, Wht, Urt,
            (t < T_ - 1) ? 1 : 0);
    }

    k_root<<<dim3(B_), dim3(256), 0, stream>>>(root_wid, root_nei, h, eWo, Wo, root_out);
}